// Round 9
// baseline (474.088 us; speedup 1.0000x reference)
//
#include <hip/hip_runtime.h>
#include <hip/hip_bf16.h>
#include <stdint.h>

// Problem: B=16, C=256, H=W=64 -> N=4096, DA=64. Inputs runtime-detected f32/bf16.
// ws layout: Q [B][N][64] bf16 | K [B][N][64] bf16 | Vt [B][C][N] bf16 (48 MB)

#define B_  16
#define C_  256
#define N_  4096
#define DA_ 64
#define MSHIFT 2.0f   // fixed softmax shift (exact: softmax invariant to constant shift)

typedef __attribute__((ext_vector_type(8))) short short8;   // 8 x bf16 bits
typedef __attribute__((ext_vector_type(4))) float f32x4;    // MFMA accumulator

__device__ int g_isf32;

__device__ __forceinline__ short f2bf(float f) {
    union { float f; uint32_t u; } v; v.f = f;
    uint32_t r = v.u + 0x7fffu + ((v.u >> 16) & 1u);   // RNE
    return (short)(r >> 16);
}
__device__ __forceinline__ float bf2f(uint16_t s) {
    union { uint32_t u; float f; } v; v.u = ((uint32_t)s) << 16;
    return v.f;
}
__device__ __forceinline__ uint32_t pkbf(float a, float b) {   // v_cvt_pk_bf16_f32
    union { __hip_bfloat162 h; uint32_t u; } c;
    c.h = __float22bfloat162_rn(make_float2(a, b));
    return c.u;
}

// dtype probe: even uint16s of f32 data hit the bf16-exponent band ~8%;
// real bf16 N(0,1) data ~100%.
__global__ void detect_kernel(const void* __restrict__ x) {
    const uint16_t* p = (const uint16_t*)x;
    int i = threadIdx.x;
    uint16_t u = p[2 * i];
    int e = (u >> 7) & 0xFF;
    unsigned long long m = __ballot(e >= 112 && e <= 132);
    if (i == 0) g_isf32 = (__popcll(m) < 32) ? 1 : 0;
}

// ---------------------------------------------------------------------------
// Kernel 1: fused QKV projection (unchanged).
// ---------------------------------------------------------------------------
template<bool F32>
__device__ __forceinline__ void proj_body(
    const void* __restrict__ xv,
    const void* __restrict__ Wqv, const void* __restrict__ bqv,
    const void* __restrict__ Wkv, const void* __restrict__ bkv,
    const void* __restrict__ Wvv, const void* __restrict__ bvv,
    uint16_t* __restrict__ Q, uint16_t* __restrict__ K, uint16_t* __restrict__ Vt,
    float* bias_lds, uint16_t* buf)
{
    const int tid = threadIdx.x;
    const int b  = blockIdx.x >> 6;
    const int n0 = (blockIdx.x & 63) * 64;
    const int w = tid >> 6, lane = tid & 63, q = lane >> 4, ln = lane & 15;

    for (int idx = tid; idx < 384; idx += 256) {
        float bias;
        if (F32) {
            bias = (idx < 64)  ? ((const float*)bqv)[idx]
                 : (idx < 128) ? ((const float*)bkv)[idx - 64]
                               : ((const float*)bvv)[idx - 128];
        } else {
            bias = (idx < 64)  ? bf2f(((const uint16_t*)bqv)[idx])
                 : (idx < 128) ? bf2f(((const uint16_t*)bkv)[idx - 64])
                               : bf2f(((const uint16_t*)bvv)[idx - 128]);
        }
        bias_lds[idx] = bias;
    }

    // ---- stage x[b][0..256][n0..n0+64] into buf as [n][c], stride 264 ----
    {
        int cbase = tid >> 2, s0 = tid & 3;
        #pragma unroll
        for (int cc = 0; cc < 4; cc++) {
            int c = cc * 64 + cbase;
            if (F32) {
                const float* xr = (const float*)xv + ((size_t)b * C_ + c) * N_ + n0;
                #pragma unroll
                for (int k = 0; k < 4; k++) {
                    int nl = (s0 + 4 * k) * 4;
                    float4 v = *(const float4*)(xr + nl);
                    buf[(nl + 0) * 264 + c] = (uint16_t)f2bf(v.x);
                    buf[(nl + 1) * 264 + c] = (uint16_t)f2bf(v.y);
                    buf[(nl + 2) * 264 + c] = (uint16_t)f2bf(v.z);
                    buf[(nl + 3) * 264 + c] = (uint16_t)f2bf(v.w);
                }
            } else {
                const uint16_t* xr = (const uint16_t*)xv + ((size_t)b * C_ + c) * N_ + n0;
                #pragma unroll
                for (int k = 0; k < 2; k++) {
                    int nl = s0 * 16 + k * 8;
                    short8 v = *(const short8*)(xr + nl);
                    #pragma unroll
                    for (int e = 0; e < 8; e++)
                        buf[(nl + e) * 264 + c] = (uint16_t)v[e];
                }
            }
        }
    }
    __syncthreads();

    f32x4 acc[6][4];
    #pragma unroll
    for (int mt = 0; mt < 6; mt++)
        #pragma unroll
        for (int nt = 0; nt < 4; nt++) acc[mt][nt] = (f32x4)0.0f;

    for (int kc = 0; kc < 8; kc++) {
        short8 af[6];
        #pragma unroll
        for (int mt = 0; mt < 6; mt++) {
            int row = (w * 6 + mt) * 16 + ln;            // 0..383
            if (F32) {
                const float* src = (row < 64) ? (const float*)Wqv + (size_t)row * 256
                                 : (row < 128) ? (const float*)Wkv + (size_t)(row - 64) * 256
                                               : (const float*)Wvv + (size_t)(row - 128) * 256;
                float4 a0 = *(const float4*)(src + kc * 32 + q * 8);
                float4 a1 = *(const float4*)(src + kc * 32 + q * 8 + 4);
                union { short8 s; uint32_t u[4]; } c;
                c.u[0] = pkbf(a0.x, a0.y); c.u[1] = pkbf(a0.z, a0.w);
                c.u[2] = pkbf(a1.x, a1.y); c.u[3] = pkbf(a1.z, a1.w);
                af[mt] = c.s;
            } else {
                const uint16_t* src = (row < 64) ? (const uint16_t*)Wqv + (size_t)row * 256
                                    : (row < 128) ? (const uint16_t*)Wkv + (size_t)(row - 64) * 256
                                                  : (const uint16_t*)Wvv + (size_t)(row - 128) * 256;
                af[mt] = *(const short8*)(src + kc * 32 + q * 8);
            }
        }
        short8 bfr[4];
        #pragma unroll
        for (int nt = 0; nt < 4; nt++)
            bfr[nt] = *(const short8*)&buf[(nt * 16 + ln) * 264 + kc * 32 + q * 8];
        #pragma unroll
        for (int mt = 0; mt < 6; mt++)
            #pragma unroll
            for (int nt = 0; nt < 4; nt++)
                acc[mt][nt] = __builtin_amdgcn_mfma_f32_16x16x32_bf16(
                    af[mt], bfr[nt], acc[mt][nt], 0, 0, 0);
    }
    __syncthreads();   // x-stage reads done; buf becomes out-stage

    // C/D layout: col = lane&15, row = quad*4 + reg
    #pragma unroll
    for (int mt = 0; mt < 6; mt++) {
        int rowb = (w * 6 + mt) * 16 + q * 4;
        #pragma unroll
        for (int r = 0; r < 4; r++) {
            float bias = bias_lds[rowb + r];
            #pragma unroll
            for (int nt = 0; nt < 4; nt++)
                buf[(rowb + r) * 72 + nt * 16 + ln] =
                    (uint16_t)f2bf(acc[mt][nt][r] + bias);
        }
    }
    __syncthreads();

    {   // Q/K: [b][n][a]
        int a = tid & 63, nb = tid >> 6;
        uint16_t* Qb = Q + ((size_t)b * N_ + n0) * 64;
        uint16_t* Kb = K + ((size_t)b * N_ + n0) * 64;
        #pragma unroll 4
        for (int j = 0; j < 16; j++) {
            int n = nb + 4 * j;
            Qb[(size_t)n * 64 + a] = buf[a * 72 + n];
            Kb[(size_t)n * 64 + a] = buf[(64 + a) * 72 + n];
        }
    }
    {   // V: [b][c][n]
        int ch = tid & 7;
        #pragma unroll
        for (int p = 0; p < 8; p++) {
            int c = p * 32 + (tid >> 3);
            short8 v = *(const short8*)&buf[(128 + c) * 72 + ch * 8];
            *(short8*)(Vt + ((size_t)b * C_ + c) * N_ + n0 + ch * 8) = v;
        }
    }
}

__global__ __launch_bounds__(256, 2) void proj_kernel(
    const void* xv, const void* Wqv, const void* bqv, const void* Wkv,
    const void* bkv, const void* Wvv, const void* bvv,
    uint16_t* Q, uint16_t* K, uint16_t* Vt)
{
    __shared__ float    bias_lds[384];
    __shared__ uint16_t buf[384 * 72];   // 55.3 KB, dual-use (x-stage / out-stage)
    if (g_isf32) proj_body<true >(xv, Wqv, bqv, Wkv, bkv, Wvv, bvv, Q, K, Vt, bias_lds, buf);
    else         proj_body<false>(xv, Wqv, bqv, Wkv, bkv, Wvv, bvv, Q, K, Vt, bias_lds, buf);
}

// ---------------------------------------------------------------------------
// Kernel 2: flash attention + residual.
// Round 9 = A/B-isolated merge of the two verified-good components:
//   - Round-6 BODY STRUCTURE (311us): V[it] issued at TOP of body (full
//     QK+softmax+barrier prefetch distance before PV consumes it — round 8
//     proved moving this issue point late costs ~10%), then QK(it) ->
//     softmax(it) -> K[it+1] ds_write -> single barrier -> PV(it).
//   - Round-8 K-WRITE ORDER (conflicts 1.68e7 -> 4.2e6): thread covers row
//     w*16+(tid&15), chunk (tid>>4)&3 -> lanes 0..7 write consecutive
//     granules (distinct bank quads). Round 6's tid&3 chunk order was a
//     4-way bank-quad collision costing ~49k cyc/CU.
//   - Refinement vs round 6: pre-barrier drain is vmcnt(8), not vmcnt(0):
//     kregs are the 2 oldest of 10 outstanding VMEM; the 8 V loads stay in
//     flight across the barrier (consumed post-barrier in PV).
// Kept: 4-wave block i-tile 64 (3 blocks/CU), XCD batch clustering
// (FETCH 250->75MB), fragment-major K/P LDS layouts, ping-pong buffers,
// fixed-shift softmax (exact). Safety identical to round 6 (ran clean).
// ---------------------------------------------------------------------------
template<bool F32>
__device__ __forceinline__ void flash_body(
    const uint16_t* __restrict__ Q, const uint16_t* __restrict__ K,
    const uint16_t* __restrict__ Vt, const void* __restrict__ xv,
    void* __restrict__ outv,
    uint16_t* Klds2, uint16_t* Plds2, float* l_lds)
{
    const int tid = threadIdx.x;
    const int d  = blockIdx.x;
    const int xc = d & 7, rest = d >> 3;
    const int b  = xc + ((rest >= 64) ? 8 : 0);
    const int i0 = (rest & 63) * 64;
    const int w = tid >> 6, lane = tid & 63, q = lane >> 4, ln = lane & 15;

    const float c1 = 1.4426950408889634f / 64.0f;  // log2(e)/sqrt(N)

    short8 qf[2];
    {
        const uint16_t* qrow = Q + ((size_t)b * N_ + (i0 + w * 16 + ln)) * 64;
        qf[0] = *(const short8*)(qrow + q * 8);
        qf[1] = *(const short8*)(qrow + 32 + q * 8);
    }

    const uint16_t* Kb = K + (size_t)b * N_ * 64;
    const uint16_t* vr0 = Vt + ((size_t)b * C_ + (w * 64 +  0 + ln)) * N_ + q * 8;
    const uint16_t* vr1 = Vt + ((size_t)b * C_ + (w * 64 + 16 + ln)) * N_ + q * 8;
    const uint16_t* vr2 = Vt + ((size_t)b * C_ + (w * 64 + 32 + ln)) * N_ + q * 8;
    const uint16_t* vr3 = Vt + ((size_t)b * C_ + (w * 64 + 48 + ln)) * N_ + q * 8;

    // K staging, conflict-free write order (round-8 fix): thread covers row
    // w*16+(tid&15), chunk (tid>>4)&3. granule = w*128 + kc4*16 + ln2 ->
    // lanes 0..7 write consecutive granules (distinct bank quads).
    const int ln2 = tid & 15, kc4 = (tid >> 4) & 3;
    const size_t kgoff = (size_t)(w * 16 + ln2) * 64 + (size_t)(kc4 * 8);
    const int kg0 = (w * 128 + kc4 * 16 + ln2) * 8;   // LDS shorts

    // P write base (shorts), fragment-major (verified round 6)
    const int pbase = (w * 128 + (q >> 1) * 16 + ln) * 8 + (q & 1) * 4;

    float l_run = 0.0f;
    f32x4 O[4][4];   // rows rg*16+q*4+e, ch w*64+ct*16+ln
    #pragma unroll
    for (int rg = 0; rg < 4; rg++)
        #pragma unroll
        for (int ct = 0; ct < 4; ct++) O[rg][ct] = (f32x4)0.0f;

    // ---- prologue: K[0] -> Klds buf0 (fragment-major) ----
    {
        short8 k0 = *(const short8*)(Kb + kgoff);
        short8 k1 = *(const short8*)(Kb + kgoff + 32);
        *(short8*)&Klds2[kg0]       = k0;
        *(short8*)&Klds2[kg0 + 512] = k1;
    }
    __syncthreads();

    for (int it = 0; it < 64; it++) {
        const int j0 = it * 64;
        const int cur = it & 1;
        const uint16_t* Kc = Klds2 + cur * 4096;
        uint16_t*       Kn = Klds2 + (cur ^ 1) * 4096;
        uint16_t*       Pl = Plds2 + cur * 4096;

        // ---- issue-early: K[it+1] into regs (oldest VMEM of the body)
        short8 kreg0, kreg1;
        if (it < 63) {
            kreg0 = *(const short8*)(Kb + (size_t)(j0 + 64) * 64 + kgoff);
            kreg1 = *(const short8*)(Kb + (size_t)(j0 + 64) * 64 + kgoff + 32);
        }

        // ---- issue-early: V[it] fragments (consumed in PV, one barrier away)
        short8 v00 = *(const short8*)(vr0 + j0);
        short8 v01 = *(const short8*)(vr1 + j0);
        short8 v02 = *(const short8*)(vr2 + j0);
        short8 v03 = *(const short8*)(vr3 + j0);
        short8 v10 = *(const short8*)(vr0 + j0 + 32);
        short8 v11 = *(const short8*)(vr1 + j0 + 32);
        short8 v12 = *(const short8*)(vr2 + j0 + 32);
        short8 v13 = *(const short8*)(vr3 + j0 + 32);

        // S: lane owns query row i = i0 + w*16 + ln, j = jt*16 + q*4 + r
        f32x4 s[4];
        #pragma unroll
        for (int jt = 0; jt < 4; jt++) s[jt] = (f32x4)0.0f;
        #pragma unroll
        for (int jt = 0; jt < 4; jt++) {
            short8 kf0 = *(const short8*)&Kc[lane * 8 + jt * 1024];
            s[jt] = __builtin_amdgcn_mfma_f32_16x16x32_bf16(kf0, qf[0], s[jt], 0, 0, 0);
            short8 kf1 = *(const short8*)&Kc[lane * 8 + jt * 1024 + 512];
            s[jt] = __builtin_amdgcn_mfma_f32_16x16x32_bf16(kf1, qf[1], s[jt], 0, 0, 0);
        }

        // fixed-shift softmax numerators; P written fragment-major
        #pragma unroll
        for (int jt = 0; jt < 4; jt++) {
            float p0 = exp2f(s[jt][0] * c1 - MSHIFT);
            float p1 = exp2f(s[jt][1] * c1 - MSHIFT);
            float p2 = exp2f(s[jt][2] * c1 - MSHIFT);
            float p3 = exp2f(s[jt][3] * c1 - MSHIFT);
            l_run += (p0 + p1) + (p2 + p3);
            uint2 pk; pk.x = pkbf(p0, p1); pk.y = pkbf(p2, p3);
            *(uint2*)&Pl[pbase + jt * 256] = pk;
        }

        // write-late K[it+1] pre-barrier. vmcnt(8): kregs are the 2 oldest of
        // 10 outstanding; the 8 V loads stay in flight across the barrier.
        if (it < 63) {
            asm volatile("s_waitcnt vmcnt(8)" ::: "memory");
            *(short8*)&Kn[kg0]       = kreg0;
            *(short8*)&Kn[kg0 + 512] = kreg1;
        }

        // SINGLE barrier: P[it] + K[it+1] visible
        asm volatile("s_waitcnt lgkmcnt(0)\n\ts_barrier" ::: "memory");

        // PV: A-frags (P, all 64 rows) from LDS, B-frags (V) from prefetched regs
        {
            short8 af[4];
            #pragma unroll
            for (int rg = 0; rg < 4; rg++)
                af[rg] = *(const short8*)&Pl[lane * 8 + rg * 1024];
            #pragma unroll
            for (int rg = 0; rg < 4; rg++) {
                O[rg][0] = __builtin_amdgcn_mfma_f32_16x16x32_bf16(af[rg], v00, O[rg][0], 0, 0, 0);
                O[rg][1] = __builtin_amdgcn_mfma_f32_16x16x32_bf16(af[rg], v01, O[rg][1], 0, 0, 0);
                O[rg][2] = __builtin_amdgcn_mfma_f32_16x16x32_bf16(af[rg], v02, O[rg][2], 0, 0, 0);
                O[rg][3] = __builtin_amdgcn_mfma_f32_16x16x32_bf16(af[rg], v03, O[rg][3], 0, 0, 0);
            }
            #pragma unroll
            for (int rg = 0; rg < 4; rg++)
                af[rg] = *(const short8*)&Pl[lane * 8 + rg * 1024 + 512];
            #pragma unroll
            for (int rg = 0; rg < 4; rg++) {
                O[rg][0] = __builtin_amdgcn_mfma_f32_16x16x32_bf16(af[rg], v10, O[rg][0], 0, 0, 0);
                O[rg][1] = __builtin_amdgcn_mfma_f32_16x16x32_bf16(af[rg], v11, O[rg][1], 0, 0, 0);
                O[rg][2] = __builtin_amdgcn_mfma_f32_16x16x32_bf16(af[rg], v12, O[rg][2], 0, 0, 0);
                O[rg][3] = __builtin_amdgcn_mfma_f32_16x16x32_bf16(af[rg], v13, O[rg][3], 0, 0, 0);
            }
        }
    }

    // finalize l: sum the 4 q-replicas (each holds a disjoint j subset)
    l_run += __shfl_xor(l_run, 16);
    l_run += __shfl_xor(l_run, 32);
    if (lane < 16) l_lds[w * 16 + lane] = l_run;
    __syncthreads();

    // epilogue: O/l + x, stored direct from registers (4 consecutive n per lane)
    #pragma unroll
    for (int rg = 0; rg < 4; rg++) {
        f32x4 lv = *(const f32x4*)&l_lds[rg * 16 + q * 4];
        f32x4 li; li[0] = 1.0f/lv[0]; li[1] = 1.0f/lv[1]; li[2] = 1.0f/lv[2]; li[3] = 1.0f/lv[3];
        #pragma unroll
        for (int ct = 0; ct < 4; ct++) {
            int c = w * 64 + ct * 16 + ln;
            size_t off = (size_t)c * N_ + i0 + rg * 16 + q * 4;
            if (F32) {
                const float* xb = (const float*)xv + (size_t)b * C_ * N_;
                float* ob = (float*)outv + (size_t)b * C_ * N_;
                float4 xv4 = *(const float4*)(xb + off);
                float4 res;
                res.x = O[rg][ct][0] * li[0] + xv4.x;
                res.y = O[rg][ct][1] * li[1] + xv4.y;
                res.z = O[rg][ct][2] * li[2] + xv4.z;
                res.w = O[rg][ct][3] * li[3] + xv4.w;
                *(float4*)(ob + off) = res;
            } else {
                const uint16_t* xb = (const uint16_t*)xv + (size_t)b * C_ * N_;
                uint16_t* ob = (uint16_t*)outv + (size_t)b * C_ * N_;
                uint2 xp = *(const uint2*)(xb + off);
                uint2 res;
                res.x = pkbf(O[rg][ct][0] * li[0] + bf2f((uint16_t)(xp.x & 0xFFFF)),
                             O[rg][ct][1] * li[1] + bf2f((uint16_t)(xp.x >> 16)));
                res.y = pkbf(O[rg][ct][2] * li[2] + bf2f((uint16_t)(xp.y & 0xFFFF)),
                             O[rg][ct][3] * li[3] + bf2f((uint16_t)(xp.y >> 16)));
                *(uint2*)(ob + off) = res;
            }
        }
    }
}

__global__ __launch_bounds__(256, 3) void flash_kernel(
    const uint16_t* Q, const uint16_t* K, const uint16_t* Vt,
    const void* xv, void* outv)
{
    __shared__ uint16_t Klds2[2 * 4096];   // 16 KB, ping-pong, fragment-major
    __shared__ uint16_t Plds2[2 * 4096];   // 16 KB, ping-pong, fragment-major
    __shared__ __align__(16) float l_lds[64];
    if (g_isf32) flash_body<true >(Q, K, Vt, xv, outv, Klds2, Plds2, l_lds);
    else         flash_body<false>(Q, K, Vt, xv, outv, Klds2, Plds2, l_lds);
}

extern "C" void kernel_launch(void* const* d_in, const int* in_sizes, int n_in,
                              void* d_out, int out_size, void* d_ws, size_t ws_size,
                              hipStream_t stream) {
    const void* x  = d_in[0];
    const void* Wq = d_in[1];
    const void* bq = d_in[2];
    const void* Wk = d_in[3];
    const void* bk = d_in[4];
    const void* Wv = d_in[5];
    const void* bv = d_in[6];

    uint16_t* Qw = (uint16_t*)d_ws;
    uint16_t* Kw = Qw + (size_t)B_ * N_ * DA_;
    uint16_t* Vw = Kw + (size_t)B_ * N_ * DA_;

    detect_kernel<<<dim3(1), dim3(64), 0, stream>>>(x);
    proj_kernel<<<dim3(B_ * 64), dim3(256), 0, stream>>>(x, Wq, bq, Wk, bk, Wv, bv, Qw, Kw, Vw);
    flash_kernel<<<dim3(B_ * 64), dim3(256), 0, stream>>>(Qw, Kw, Vw, x, d_out);
}

// Round 10
// 434.334 us; speedup vs baseline: 1.0915x; 1.0915x over previous
//
#include <hip/hip_runtime.h>
#include <hip/hip_bf16.h>
#include <stdint.h>

// Problem: B=16, C=256, H=W=64 -> N=4096, DA=64. Inputs runtime-detected f32/bf16.
// ws layout: Q [B][N][64] bf16 | K [B][N][64] bf16 | Vt [B][C][N] bf16 (48 MB)

#define B_  16
#define C_  256
#define N_  4096
#define DA_ 64
#define MSHIFT 2.0f   // fixed softmax shift (exact: softmax invariant to constant shift)

typedef __attribute__((ext_vector_type(8))) short short8;   // 8 x bf16 bits
typedef __attribute__((ext_vector_type(4))) float f32x4;    // MFMA accumulator

__device__ int g_isf32;

__device__ __forceinline__ short f2bf(float f) {
    union { float f; uint32_t u; } v; v.f = f;
    uint32_t r = v.u + 0x7fffu + ((v.u >> 16) & 1u);   // RNE
    return (short)(r >> 16);
}
__device__ __forceinline__ float bf2f(uint16_t s) {
    union { uint32_t u; float f; } v; v.u = ((uint32_t)s) << 16;
    return v.f;
}
__device__ __forceinline__ uint32_t pkbf(float a, float b) {   // v_cvt_pk_bf16_f32
    union { __hip_bfloat162 h; uint32_t u; } c;
    c.h = __float22bfloat162_rn(make_float2(a, b));
    return c.u;
}

// dtype probe: even uint16s of f32 data hit the bf16-exponent band ~8%;
// real bf16 N(0,1) data ~100%.
__global__ void detect_kernel(const void* __restrict__ x) {
    const uint16_t* p = (const uint16_t*)x;
    int i = threadIdx.x;
    uint16_t u = p[2 * i];
    int e = (u >> 7) & 0xFF;
    unsigned long long m = __ballot(e >= 112 && e <= 132);
    if (i == 0) g_isf32 = (__popcll(m) < 32) ? 1 : 0;
}

// ---------------------------------------------------------------------------
// Kernel 1: fused QKV projection (unchanged).
// ---------------------------------------------------------------------------
template<bool F32>
__device__ __forceinline__ void proj_body(
    const void* __restrict__ xv,
    const void* __restrict__ Wqv, const void* __restrict__ bqv,
    const void* __restrict__ Wkv, const void* __restrict__ bkv,
    const void* __restrict__ Wvv, const void* __restrict__ bvv,
    uint16_t* __restrict__ Q, uint16_t* __restrict__ K, uint16_t* __restrict__ Vt,
    float* bias_lds, uint16_t* buf)
{
    const int tid = threadIdx.x;
    const int b  = blockIdx.x >> 6;
    const int n0 = (blockIdx.x & 63) * 64;
    const int w = tid >> 6, lane = tid & 63, q = lane >> 4, ln = lane & 15;

    for (int idx = tid; idx < 384; idx += 256) {
        float bias;
        if (F32) {
            bias = (idx < 64)  ? ((const float*)bqv)[idx]
                 : (idx < 128) ? ((const float*)bkv)[idx - 64]
                               : ((const float*)bvv)[idx - 128];
        } else {
            bias = (idx < 64)  ? bf2f(((const uint16_t*)bqv)[idx])
                 : (idx < 128) ? bf2f(((const uint16_t*)bkv)[idx - 64])
                               : bf2f(((const uint16_t*)bvv)[idx - 128]);
        }
        bias_lds[idx] = bias;
    }

    // ---- stage x[b][0..256][n0..n0+64] into buf as [n][c], stride 264 ----
    {
        int cbase = tid >> 2, s0 = tid & 3;
        #pragma unroll
        for (int cc = 0; cc < 4; cc++) {
            int c = cc * 64 + cbase;
            if (F32) {
                const float* xr = (const float*)xv + ((size_t)b * C_ + c) * N_ + n0;
                #pragma unroll
                for (int k = 0; k < 4; k++) {
                    int nl = (s0 + 4 * k) * 4;
                    float4 v = *(const float4*)(xr + nl);
                    buf[(nl + 0) * 264 + c] = (uint16_t)f2bf(v.x);
                    buf[(nl + 1) * 264 + c] = (uint16_t)f2bf(v.y);
                    buf[(nl + 2) * 264 + c] = (uint16_t)f2bf(v.z);
                    buf[(nl + 3) * 264 + c] = (uint16_t)f2bf(v.w);
                }
            } else {
                const uint16_t* xr = (const uint16_t*)xv + ((size_t)b * C_ + c) * N_ + n0;
                #pragma unroll
                for (int k = 0; k < 2; k++) {
                    int nl = s0 * 16 + k * 8;
                    short8 v = *(const short8*)(xr + nl);
                    #pragma unroll
                    for (int e = 0; e < 8; e++)
                        buf[(nl + e) * 264 + c] = (uint16_t)v[e];
                }
            }
        }
    }
    __syncthreads();

    f32x4 acc[6][4];
    #pragma unroll
    for (int mt = 0; mt < 6; mt++)
        #pragma unroll
        for (int nt = 0; nt < 4; nt++) acc[mt][nt] = (f32x4)0.0f;

    for (int kc = 0; kc < 8; kc++) {
        short8 af[6];
        #pragma unroll
        for (int mt = 0; mt < 6; mt++) {
            int row = (w * 6 + mt) * 16 + ln;            // 0..383
            if (F32) {
                const float* src = (row < 64) ? (const float*)Wqv + (size_t)row * 256
                                 : (row < 128) ? (const float*)Wkv + (size_t)(row - 64) * 256
                                               : (const float*)Wvv + (size_t)(row - 128) * 256;
                float4 a0 = *(const float4*)(src + kc * 32 + q * 8);
                float4 a1 = *(const float4*)(src + kc * 32 + q * 8 + 4);
                union { short8 s; uint32_t u[4]; } c;
                c.u[0] = pkbf(a0.x, a0.y); c.u[1] = pkbf(a0.z, a0.w);
                c.u[2] = pkbf(a1.x, a1.y); c.u[3] = pkbf(a1.z, a1.w);
                af[mt] = c.s;
            } else {
                const uint16_t* src = (row < 64) ? (const uint16_t*)Wqv + (size_t)row * 256
                                    : (row < 128) ? (const uint16_t*)Wkv + (size_t)(row - 64) * 256
                                                  : (const uint16_t*)Wvv + (size_t)(row - 128) * 256;
                af[mt] = *(const short8*)(src + kc * 32 + q * 8);
            }
        }
        short8 bfr[4];
        #pragma unroll
        for (int nt = 0; nt < 4; nt++)
            bfr[nt] = *(const short8*)&buf[(nt * 16 + ln) * 264 + kc * 32 + q * 8];
        #pragma unroll
        for (int mt = 0; mt < 6; mt++)
            #pragma unroll
            for (int nt = 0; nt < 4; nt++)
                acc[mt][nt] = __builtin_amdgcn_mfma_f32_16x16x32_bf16(
                    af[mt], bfr[nt], acc[mt][nt], 0, 0, 0);
    }
    __syncthreads();   // x-stage reads done; buf becomes out-stage

    // C/D layout: col = lane&15, row = quad*4 + reg
    #pragma unroll
    for (int mt = 0; mt < 6; mt++) {
        int rowb = (w * 6 + mt) * 16 + q * 4;
        #pragma unroll
        for (int r = 0; r < 4; r++) {
            float bias = bias_lds[rowb + r];
            #pragma unroll
            for (int nt = 0; nt < 4; nt++)
                buf[(rowb + r) * 72 + nt * 16 + ln] =
                    (uint16_t)f2bf(acc[mt][nt][r] + bias);
        }
    }
    __syncthreads();

    {   // Q/K: [b][n][a]
        int a = tid & 63, nb = tid >> 6;
        uint16_t* Qb = Q + ((size_t)b * N_ + n0) * 64;
        uint16_t* Kb = K + ((size_t)b * N_ + n0) * 64;
        #pragma unroll 4
        for (int j = 0; j < 16; j++) {
            int n = nb + 4 * j;
            Qb[(size_t)n * 64 + a] = buf[a * 72 + n];
            Kb[(size_t)n * 64 + a] = buf[(64 + a) * 72 + n];
        }
    }
    {   // V: [b][c][n]
        int ch = tid & 7;
        #pragma unroll
        for (int p = 0; p < 8; p++) {
            int c = p * 32 + (tid >> 3);
            short8 v = *(const short8*)&buf[(128 + c) * 72 + ch * 8];
            *(short8*)(Vt + ((size_t)b * C_ + c) * N_ + n0 + ch * 8) = v;
        }
    }
}

__global__ __launch_bounds__(256, 2) void proj_kernel(
    const void* xv, const void* Wqv, const void* bqv, const void* Wkv,
    const void* bkv, const void* Wvv, const void* bvv,
    uint16_t* Q, uint16_t* K, uint16_t* Vt)
{
    __shared__ float    bias_lds[384];
    __shared__ uint16_t buf[384 * 72];   // 55.3 KB, dual-use (x-stage / out-stage)
    if (g_isf32) proj_body<true >(xv, Wqv, bqv, Wkv, bkv, Wvv, bvv, Q, K, Vt, bias_lds, buf);
    else         proj_body<false>(xv, Wqv, bqv, Wkv, bkv, Wvv, bvv, Q, K, Vt, bias_lds, buf);
}

// ---------------------------------------------------------------------------
// Kernel 2: flash attention + residual.
// Round 10 = round-6 kernel (311us, best) + ONE isolated change: XOR-swizzled
// K LDS addressing that is conflict-free WITHOUT changing the global mapping.
//
// Round-9 lesson: remapping threads (ln2=tid&15) fixed LDS banks but made
// consecutive lanes 128B apart in GLOBAL memory (uncoalesced scatter) ->
// 347us. The two constraints decouple via an address swizzle instead:
//   global mapping (round 6, coalesced): thread t -> K row t>>2, chunk t&3
//     (4 consecutive lanes cover a contiguous 64B segment).
//   LDS: content granule c = W*128 + kst*64 + kc4*16 + (row&15) stored at
//     PHYSICAL granule p = c ^ ((c>>3)&6)  (XOR c bits 4-5 into bits 1-2).
//   Write groups (8 lanes: kc4 0..3, row&1 0..1): p%8 = (row&15)^(2*kc4)
//     -> {0..7} distinct -> conflict-free.
//   Read side folds to lane_sw = lane ^ ((lane>>3)&6) precomputed once
//     (jt*128+kst*64 is a multiple of 64 so the swizzle term is lane-only);
//   read groups: p%8 = lane%8 ^ const -> distinct. kst=1 granule c+64 ->
//     p+64 (bit 6 untouched) so the +512-short offset is unchanged.
// vmcnt reverted to (0) as in round 6 (vmcnt(8) was confounded with the
// round-9 regression; retest separately if this lands).
//
// Kept: 4-wave block i-tile 64 (3 blocks/CU), XCD batch clustering,
// V 8-reg issue-early prefetch at body top, K issue-early/write-late,
// fragment-major P layout, ping-pong buffers, single barrier/iter,
// fixed-shift softmax (exact).
// ---------------------------------------------------------------------------
template<bool F32>
__device__ __forceinline__ void flash_body(
    const uint16_t* __restrict__ Q, const uint16_t* __restrict__ K,
    const uint16_t* __restrict__ Vt, const void* __restrict__ xv,
    void* __restrict__ outv,
    uint16_t* Klds2, uint16_t* Plds2, float* l_lds)
{
    const int tid = threadIdx.x;
    const int d  = blockIdx.x;
    const int xc = d & 7, rest = d >> 3;
    const int b  = xc + ((rest >= 64) ? 8 : 0);
    const int i0 = (rest & 63) * 64;
    const int w = tid >> 6, lane = tid & 63, q = lane >> 4, ln = lane & 15;

    const float c1 = 1.4426950408889634f / 64.0f;  // log2(e)/sqrt(N)

    short8 qf[2];
    {
        const uint16_t* qrow = Q + ((size_t)b * N_ + (i0 + w * 16 + ln)) * 64;
        qf[0] = *(const short8*)(qrow + q * 8);
        qf[1] = *(const short8*)(qrow + 32 + q * 8);
    }

    const uint16_t* Kb = K + (size_t)b * N_ * 64;
    const uint16_t* vr0 = Vt + ((size_t)b * C_ + (w * 64 +  0 + ln)) * N_ + q * 8;
    const uint16_t* vr1 = Vt + ((size_t)b * C_ + (w * 64 + 16 + ln)) * N_ + q * 8;
    const uint16_t* vr2 = Vt + ((size_t)b * C_ + (w * 64 + 32 + ln)) * N_ + q * 8;
    const uint16_t* vr3 = Vt + ((size_t)b * C_ + (w * 64 + 48 + ln)) * N_ + q * 8;

    // K staging: COALESCED global mapping (round 6): thread t covers K row
    // krow=t>>2, chunks (t&3) [kst=0 at +0, kst=1 at +32 shorts].
    const int krow = tid >> 2, kc4 = tid & 3;
    const size_t kgoff = (size_t)krow * 64 + (size_t)(kc4 * 8);   // global shorts
    // LDS physical granule: p = c ^ ((c>>3)&6), c = (krow>>4)*128+kc4*16+(krow&15)
    const int kg0 = ((krow >> 4) * 128 + kc4 * 16 + ((krow & 15) ^ (kc4 << 1))) * 8;
    // QK read swizzle: physical = const + lane_sw
    const int lane_sw = lane ^ ((lane >> 3) & 6);

    // P write base (shorts), fragment-major (verified round 6)
    const int pbase = (w * 128 + (q >> 1) * 16 + ln) * 8 + (q & 1) * 4;

    float l_run = 0.0f;
    f32x4 O[4][4];   // rows rg*16+q*4+e, ch w*64+ct*16+ln
    #pragma unroll
    for (int rg = 0; rg < 4; rg++)
        #pragma unroll
        for (int ct = 0; ct < 4; ct++) O[rg][ct] = (f32x4)0.0f;

    // ---- prologue: K[0] -> Klds buf0 (fragment-major, swizzled) ----
    {
        short8 k0 = *(const short8*)(Kb + kgoff);
        short8 k1 = *(const short8*)(Kb + kgoff + 32);
        *(short8*)&Klds2[kg0]       = k0;
        *(short8*)&Klds2[kg0 + 512] = k1;
    }
    __syncthreads();

    for (int it = 0; it < 64; it++) {
        const int j0 = it * 64;
        const int cur = it & 1;
        const uint16_t* Kc = Klds2 + cur * 4096;
        uint16_t*       Kn = Klds2 + (cur ^ 1) * 4096;
        uint16_t*       Pl = Plds2 + cur * 4096;

        // ---- issue-early: K[it+1] into regs (oldest VMEM of the body)
        short8 kreg0, kreg1;
        if (it < 63) {
            kreg0 = *(const short8*)(Kb + (size_t)(j0 + 64) * 64 + kgoff);
            kreg1 = *(const short8*)(Kb + (size_t)(j0 + 64) * 64 + kgoff + 32);
        }

        // ---- issue-early: V[it] fragments (consumed in PV, one barrier away)
        short8 v00 = *(const short8*)(vr0 + j0);
        short8 v01 = *(const short8*)(vr1 + j0);
        short8 v02 = *(const short8*)(vr2 + j0);
        short8 v03 = *(const short8*)(vr3 + j0);
        short8 v10 = *(const short8*)(vr0 + j0 + 32);
        short8 v11 = *(const short8*)(vr1 + j0 + 32);
        short8 v12 = *(const short8*)(vr2 + j0 + 32);
        short8 v13 = *(const short8*)(vr3 + j0 + 32);

        // S: lane owns query row i = i0 + w*16 + ln, j = jt*16 + q*4 + r
        f32x4 s[4];
        #pragma unroll
        for (int jt = 0; jt < 4; jt++) s[jt] = (f32x4)0.0f;
        #pragma unroll
        for (int jt = 0; jt < 4; jt++) {
            short8 kf0 = *(const short8*)&Kc[lane_sw * 8 + jt * 1024];
            s[jt] = __builtin_amdgcn_mfma_f32_16x16x32_bf16(kf0, qf[0], s[jt], 0, 0, 0);
            short8 kf1 = *(const short8*)&Kc[lane_sw * 8 + jt * 1024 + 512];
            s[jt] = __builtin_amdgcn_mfma_f32_16x16x32_bf16(kf1, qf[1], s[jt], 0, 0, 0);
        }

        // fixed-shift softmax numerators; P written fragment-major
        #pragma unroll
        for (int jt = 0; jt < 4; jt++) {
            float p0 = exp2f(s[jt][0] * c1 - MSHIFT);
            float p1 = exp2f(s[jt][1] * c1 - MSHIFT);
            float p2 = exp2f(s[jt][2] * c1 - MSHIFT);
            float p3 = exp2f(s[jt][3] * c1 - MSHIFT);
            l_run += (p0 + p1) + (p2 + p3);
            uint2 pk; pk.x = pkbf(p0, p1); pk.y = pkbf(p2, p3);
            *(uint2*)&Pl[pbase + jt * 256] = pk;
        }

        // write-late K[it+1] pre-barrier (kreg issued a full phase ago)
        if (it < 63) {
            asm volatile("s_waitcnt vmcnt(0)" ::: "memory");
            *(short8*)&Kn[kg0]       = kreg0;
            *(short8*)&Kn[kg0 + 512] = kreg1;
        }

        // SINGLE barrier: P[it] + K[it+1] visible
        asm volatile("s_waitcnt lgkmcnt(0)\n\ts_barrier" ::: "memory");

        // PV: A-frags (P, all 64 rows) from LDS, B-frags (V) from prefetched regs
        {
            short8 af[4];
            #pragma unroll
            for (int rg = 0; rg < 4; rg++)
                af[rg] = *(const short8*)&Pl[lane * 8 + rg * 1024];
            #pragma unroll
            for (int rg = 0; rg < 4; rg++) {
                O[rg][0] = __builtin_amdgcn_mfma_f32_16x16x32_bf16(af[rg], v00, O[rg][0], 0, 0, 0);
                O[rg][1] = __builtin_amdgcn_mfma_f32_16x16x32_bf16(af[rg], v01, O[rg][1], 0, 0, 0);
                O[rg][2] = __builtin_amdgcn_mfma_f32_16x16x32_bf16(af[rg], v02, O[rg][2], 0, 0, 0);
                O[rg][3] = __builtin_amdgcn_mfma_f32_16x16x32_bf16(af[rg], v03, O[rg][3], 0, 0, 0);
            }
            #pragma unroll
            for (int rg = 0; rg < 4; rg++)
                af[rg] = *(const short8*)&Pl[lane * 8 + rg * 1024 + 512];
            #pragma unroll
            for (int rg = 0; rg < 4; rg++) {
                O[rg][0] = __builtin_amdgcn_mfma_f32_16x16x32_bf16(af[rg], v10, O[rg][0], 0, 0, 0);
                O[rg][1] = __builtin_amdgcn_mfma_f32_16x16x32_bf16(af[rg], v11, O[rg][1], 0, 0, 0);
                O[rg][2] = __builtin_amdgcn_mfma_f32_16x16x32_bf16(af[rg], v12, O[rg][2], 0, 0, 0);
                O[rg][3] = __builtin_amdgcn_mfma_f32_16x16x32_bf16(af[rg], v13, O[rg][3], 0, 0, 0);
            }
        }
    }

    // finalize l: sum the 4 q-replicas (each holds a disjoint j subset)
    l_run += __shfl_xor(l_run, 16);
    l_run += __shfl_xor(l_run, 32);
    if (lane < 16) l_lds[w * 16 + lane] = l_run;
    __syncthreads();

    // epilogue: O/l + x, stored direct from registers (4 consecutive n per lane)
    #pragma unroll
    for (int rg = 0; rg < 4; rg++) {
        f32x4 lv = *(const f32x4*)&l_lds[rg * 16 + q * 4];
        f32x4 li; li[0] = 1.0f/lv[0]; li[1] = 1.0f/lv[1]; li[2] = 1.0f/lv[2]; li[3] = 1.0f/lv[3];
        #pragma unroll
        for (int ct = 0; ct < 4; ct++) {
            int c = w * 64 + ct * 16 + ln;
            size_t off = (size_t)c * N_ + i0 + rg * 16 + q * 4;
            if (F32) {
                const float* xb = (const float*)xv + (size_t)b * C_ * N_;
                float* ob = (float*)outv + (size_t)b * C_ * N_;
                float4 xv4 = *(const float4*)(xb + off);
                float4 res;
                res.x = O[rg][ct][0] * li[0] + xv4.x;
                res.y = O[rg][ct][1] * li[1] + xv4.y;
                res.z = O[rg][ct][2] * li[2] + xv4.z;
                res.w = O[rg][ct][3] * li[3] + xv4.w;
                *(float4*)(ob + off) = res;
            } else {
                const uint16_t* xb = (const uint16_t*)xv + (size_t)b * C_ * N_;
                uint16_t* ob = (uint16_t*)outv + (size_t)b * C_ * N_;
                uint2 xp = *(const uint2*)(xb + off);
                uint2 res;
                res.x = pkbf(O[rg][ct][0] * li[0] + bf2f((uint16_t)(xp.x & 0xFFFF)),
                             O[rg][ct][1] * li[1] + bf2f((uint16_t)(xp.x >> 16)));
                res.y = pkbf(O[rg][ct][2] * li[2] + bf2f((uint16_t)(xp.y & 0xFFFF)),
                             O[rg][ct][3] * li[3] + bf2f((uint16_t)(xp.y >> 16)));
                *(uint2*)(ob + off) = res;
            }
        }
    }
}

__global__ __launch_bounds__(256, 3) void flash_kernel(
    const uint16_t* Q, const uint16_t* K, const uint16_t* Vt,
    const void* xv, void* outv)
{
    __shared__ uint16_t Klds2[2 * 4096];   // 16 KB, ping-pong, fragment-major+swz
    __shared__ uint16_t Plds2[2 * 4096];   // 16 KB, ping-pong, fragment-major
    __shared__ __align__(16) float l_lds[64];
    if (g_isf32) flash_body<true >(Q, K, Vt, xv, outv, Klds2, Plds2, l_lds);
    else         flash_body<false>(Q, K, Vt, xv, outv, Klds2, Plds2, l_lds);
}

extern "C" void kernel_launch(void* const* d_in, const int* in_sizes, int n_in,
                              void* d_out, int out_size, void* d_ws, size_t ws_size,
                              hipStream_t stream) {
    const void* x  = d_in[0];
    const void* Wq = d_in[1];
    const void* bq = d_in[2];
    const void* Wk = d_in[3];
    const void* bk = d_in[4];
    const void* Wv = d_in[5];
    const void* bv = d_in[6];

    uint16_t* Qw = (uint16_t*)d_ws;
    uint16_t* Kw = Qw + (size_t)B_ * N_ * DA_;
    uint16_t* Vw = Kw + (size_t)B_ * N_ * DA_;

    detect_kernel<<<dim3(1), dim3(64), 0, stream>>>(x);
    proj_kernel<<<dim3(B_ * 64), dim3(256), 0, stream>>>(x, Wq, bq, Wk, bk, Wv, bv, Qw, Kw, Vw);
    flash_kernel<<<dim3(B_ * 64), dim3(256), 0, stream>>>(Qw, Kw, Vw, x, d_out);
}